// Round 2
// baseline (356.707 us; speedup 1.0000x reference)
//
#include <hip/hip_runtime.h>
#include <hip/hip_cooperative_groups.h>
#include <math.h>

namespace cg = cooperative_groups;

// Problem constants (B, SK, SQ, H, D, N) = (4, 4096, 4096, 16, 64, 32)
#define SK 4096
#define SQ 4096
#define HH 16
#define DD 64
#define NN 32

typedef __attribute__((ext_vector_type(8))) short short8;   // 8 bf16 = 4 VGPRs
typedef __attribute__((ext_vector_type(4))) float floatx4;  // MFMA C/D
typedef __attribute__((ext_vector_type(4))) unsigned short us4;

// freqs[n] = (n / (N-1)) * N * pi
__device__ __forceinline__ float freq_of(int n) {
    return (float)n * (32.0f * (float)M_PI / 31.0f);
}

// fp32 -> bf16 (round to nearest even), as raw ushort
__device__ __forceinline__ unsigned short f2bf(float x) {
    unsigned u = __float_as_uint(x);
    u += 0x7FFFu + ((u >> 16) & 1u);
    return (unsigned short)(u >> 16);
}

// ===========================================================================
// FUSED cooperative kernel: phase A (chunk partials, = verified k1) ->
// grid.sync -> phase R (chunk reduce) -> grid.sync -> phase B (= verified k2,
// widened to 256 q/block: CS staged once, B-frags in regs reused 4x).
// 1024 blocks x 256 threads, 4 blocks/CU co-resident (17 KB LDS, <=128 VGPR).
// ===========================================================================
static constexpr int FNC  = 16;          // chunks
static constexpr int FKPC = SK / FNC;    // 256 keys / chunk
static constexpr int FNB  = FKPC / 64;   // 4 value tiles / chunk

__global__ __launch_bounds__(256, 4) void fused(
    const float* __restrict__ key_in, const float* __restrict__ value,
    const float* __restrict__ query, const float* __restrict__ ramps,
    const float* __restrict__ iamps, float* __restrict__ P,
    float* __restrict__ CS, float* __restrict__ out)
{
    cg::grid_group grid = cg::this_grid();
    const int bid = blockIdx.x;
    const int tid = threadIdx.x;
    const int w = tid >> 6, l = tid & 63;
    const int fl = l & 15, qd = l >> 4;

    // 17408 B shared, phase-aliased:
    //  A: vtb[2][64*64] bf16 (16 KB) + kt[256] f32 (1 KB)
    //  B: cst[64*64] bf16 (8 KB) + qv[256] f32 (1 KB)
    __shared__ __align__(16) char smraw[2 * 64 * 64 * 2 + FKPC * 4];
    unsigned short (*vtb)[64 * 64] = (unsigned short (*)[64 * 64])smraw;
    float* kt = (float*)(smraw + 16384);
    unsigned short* cst = (unsigned short*)smraw;
    float* qv = (float*)(smraw + 8192);

    // ===================== Phase A: chunk partial C/S =====================
    {
        const int chunk = bid & (FNC - 1);
        const int bh    = bid / FNC;
        const int b = bh >> 4, h = bh & 15;
        const int k0 = chunk * FKPC;
        const int g  = tid & 15;           // d quad (d = 4g..4g+3)
        const int kq = tid >> 4;           // 0..15 (k' block)

        kt[tid] = key_in[(size_t)(b * SK + k0 + tid) * HH + h];

        const int feat = w * 16 + fl;
        const float fn = freq_of(feat & 31);
        const bool use_sin = (w >= 2);

        floatx4 acc[4];
        #pragma unroll
        for (int dt = 0; dt < 4; ++dt) acc[dt] = (floatx4){0.f, 0.f, 0.f, 0.f};

        union F4 { float4 v; float f[4]; };
        F4 L[2][4];

        auto vload = [&](int bb, int p) {  // 4 coalesced float4 per thread
            const int kb = k0 + bb * 64;
            #pragma unroll
            for (int jj = 0; jj < 4; ++jj)
                L[p][jj].v = *(const float4*)(value
                    + (size_t)(b * SK + kb + jj * 16 + kq) * (HH * DD) + h * DD + g * 4);
        };
        auto vstore = [&](int p) {         // cvt + packed b64 writes (swizzled)
            #pragma unroll
            for (int e = 0; e < 4; ++e) {
                const int d = g * 4 + e;
                union { us4 v; unsigned short u[4]; } px;
                #pragma unroll
                for (int jj = 0; jj < 4; ++jj)
                    px.u[jj] = f2bf(L[p][jj].f[e]);
                *(us4*)&vtb[p][d * 64 + ((((kq >> 1) ^ (d & 7)) << 3) | ((kq & 1) << 2))]
                    = px.v;
            }
        };

        vload(0, 0);
        #pragma unroll
        for (int bb = 0; bb < FNB; ++bb) {
            const int p = bb & 1;
            if (bb + 1 < FNB) vload(bb + 1, p ^ 1);   // issue next tile early
            vstore(p);
            __syncthreads();                          // vtb[p] + kt ready

            #pragma unroll
            for (int s = 0; s < 2; ++s) {  // 2 K-steps of 32 keys (k'-order)
                const int cb = bb * 64 + s * 8 + qd * 2;
                float2 p0 = *(const float2*)&kt[cb];
                float2 p1 = *(const float2*)&kt[cb + 16];
                float2 p2 = *(const float2*)&kt[cb + 32];
                float2 p3 = *(const float2*)&kt[cb + 48];
                float kj[8] = {p0.x, p1.x, p2.x, p3.x, p0.y, p1.y, p2.y, p3.y};

                union { short8 v; unsigned short u[8]; } A;
                #pragma unroll
                for (int j = 0; j < 8; ++j) {
                    float ang = fn * kj[j];
                    A.u[j] = f2bf(use_sin ? __sinf(ang) : __cosf(ang));
                }

                #pragma unroll
                for (int dt = 0; dt < 4; ++dt) {
                    const int d = dt * 16 + fl;
                    short8 B = *(const short8*)
                        &vtb[p][d * 64 + ((((s << 2) | qd) ^ (d & 7)) << 3)];
                    acc[dt] = __builtin_amdgcn_mfma_f32_16x16x32_bf16(
                        A.v, B, acc[dt], 0, 0, 0);
                }
            }
        }

        float* Pb = P + ((size_t)chunk * 64 + bh) * (2 * NN * DD);
        #pragma unroll
        for (int dt = 0; dt < 4; ++dt)
            #pragma unroll
            for (int r = 0; r < 4; ++r)
                Pb[(w * 16 + qd * 4 + r) * DD + dt * 16 + fl] = acc[dt][r];
    }

    grid.sync();

    // ===================== Phase R: reduce chunk partials =================
    {
        const int gid = bid * 256 + tid;   // 1024*256 == 64*2*NN*DD
        float a = 0.f;
        #pragma unroll
        for (int c = 0; c < FNC; ++c)
            a += P[(size_t)c * (64 * 2 * NN * DD) + gid];
        CS[gid] = a;
    }

    grid.sync();

    // ===================== Phase B: out = Aq * CS =========================
    {
        const int v0 = bid * 2;            // two q-chunks of 128 -> 256 q/block
        const int bh = v0 >> 5;
        const int b = bh >> 4, h = bh & 15;
        const int Q0 = (v0 & 31) * 128;

        // stage CS (fp32 [feat][d]) -> bf16 [d][feat] with XOR swizzle
        {
            const float* CSb = CS + (size_t)bh * (2 * NN * DD);
            const int feat = tid >> 2, dbase = (tid & 3) * 16;
            const int fb = feat >> 3, f7 = feat & 7;
            #pragma unroll
            for (int i = 0; i < 4; ++i) {
                float4 v4 = *(const float4*)&CSb[feat * DD + dbase + i * 4];
                float vv[4] = {v4.x, v4.y, v4.z, v4.w};
                #pragma unroll
                for (int e = 0; e < 4; ++e) {
                    int d = dbase + i * 4 + e;
                    cst[d * 64 + ((fb ^ (d & 7)) << 3) + f7] = f2bf(vv[e]);
                }
            }
            qv[tid] = query[(size_t)(b * SQ + Q0 + tid) * HH + h];
        }
        __syncthreads();

        const int nb = qd * 8;
        float4 raA = *(const float4*)&ramps[h * NN + nb];
        float4 raB = *(const float4*)&ramps[h * NN + nb + 4];
        float4 iaA = *(const float4*)&iamps[h * NN + nb];
        float4 iaB = *(const float4*)&iamps[h * NN + nb + 4];
        float ra[8] = {raA.x, raA.y, raA.z, raA.w, raB.x, raB.y, raB.z, raB.w};
        float ia[8] = {iaA.x, iaA.y, iaA.z, iaA.w, iaB.x, iaB.y, iaB.z, iaB.w};

        short8 B0[4], B1[4];               // held in regs, reused 4x
        #pragma unroll
        for (int dt = 0; dt < 4; ++dt) {
            const int d = dt * 16 + fl;
            B0[dt] = *(const short8*)&cst[d * 64 + ((qd ^ (d & 7)) << 3)];
            B1[dt] = *(const short8*)&cst[d * 64 + (((4 + qd) ^ (d & 7)) << 3)];
        }

        #pragma unroll
        for (int qq = 0; qq < 2; ++qq) {
            union AB { short8 v; unsigned short u[8]; };
            AB A0[2], A1[2];
            #pragma unroll
            for (int hh = 0; hh < 2; ++hh) {
                const float qval = qv[qq * 128 + hh * 64 + w * 16 + fl];
                #pragma unroll
                for (int j = 0; j < 8; ++j) {
                    float s, c;
                    __sincosf(freq_of(nb + j) * qval, &s, &c);
                    A0[hh].u[j] = f2bf(ra[j] * c + ia[j] * s);   // vs C rows
                    A1[hh].u[j] = f2bf(ra[j] * s - ia[j] * c);   // vs S rows
                }
            }
            floatx4 acc[2][4];
            #pragma unroll
            for (int hh = 0; hh < 2; ++hh)
                #pragma unroll
                for (int dt = 0; dt < 4; ++dt)
                    acc[hh][dt] = (floatx4){0.f, 0.f, 0.f, 0.f};

            #pragma unroll
            for (int dt = 0; dt < 4; ++dt)
                #pragma unroll
                for (int hh = 0; hh < 2; ++hh) {
                    acc[hh][dt] = __builtin_amdgcn_mfma_f32_16x16x32_bf16(
                        A0[hh].v, B0[dt], acc[hh][dt], 0, 0, 0);
                    acc[hh][dt] = __builtin_amdgcn_mfma_f32_16x16x32_bf16(
                        A1[hh].v, B1[dt], acc[hh][dt], 0, 0, 0);
                }

            float* ob = out + ((size_t)(b * SQ + Q0 + qq * 128) * HH + h) * DD;
            #pragma unroll
            for (int hh = 0; hh < 2; ++hh)
                #pragma unroll
                for (int dt = 0; dt < 4; ++dt)
                    #pragma unroll
                    for (int r = 0; r < 4; ++r) {
                        int q = hh * 64 + w * 16 + qd * 4 + r;
                        ob[(size_t)q * (HH * DD) + dt * 16 + fl] = acc[hh][dt][r];
                    }
        }
    }
}

// ===========================================================================
// Fallback 3-kernel path (round-1 verified kernels), used if the cooperative
// launch is rejected (e.g. under graph capture) or ws is small.
// ===========================================================================
template <int NC>
__global__ __launch_bounds__(256) void k1_partial(
    const float* __restrict__ key_in, const float* __restrict__ value,
    float* __restrict__ P)
{
    constexpr int KPC = SK / NC;
    constexpr int NB  = KPC / 64;
    const int chunk = blockIdx.x & (NC - 1);
    const int bh    = blockIdx.x / NC;
    const int b = bh >> 4, h = bh & 15;
    const int tid = threadIdx.x;
    const int w = tid >> 6, l = tid & 63;

    __shared__ unsigned short vtb[2][64 * 64];
    __shared__ float kt[KPC];

    const int k0 = chunk * KPC;
    const int g  = tid & 15;
    const int kq = tid >> 4;

    #pragma unroll
    for (int i = 0; i < KPC / 256; ++i)
        kt[tid + i * 256] = key_in[(size_t)(b * SK + k0 + tid + i * 256) * HH + h];

    const int fl = l & 15;
    const int qd = l >> 4;
    const int feat = w * 16 + fl;
    const float fn = freq_of(feat & 31);
    const bool use_sin = (w >= 2);

    floatx4 acc[4];
    #pragma unroll
    for (int dt = 0; dt < 4; ++dt) acc[dt] = (floatx4){0.f, 0.f, 0.f, 0.f};

    union F4 { float4 v; float f[4]; };
    F4 L[2][4];

    auto vload = [&](int bb, int p) {
        const int kb = k0 + bb * 64;
        #pragma unroll
        for (int jj = 0; jj < 4; ++jj)
            L[p][jj].v = *(const float4*)(value
                + (size_t)(b * SK + kb + jj * 16 + kq) * (HH * DD) + h * DD + g * 4);
    };
    auto vstore = [&](int p) {
        #pragma unroll
        for (int e = 0; e < 4; ++e) {
            const int d = g * 4 + e;
            union { us4 v; unsigned short u[4]; } px;
            #pragma unroll
            for (int jj = 0; jj < 4; ++jj)
                px.u[jj] = f2bf(L[p][jj].f[e]);
            *(us4*)&vtb[p][d * 64 + ((((kq >> 1) ^ (d & 7)) << 3) | ((kq & 1) << 2))]
                = px.v;
        }
    };

    vload(0, 0);
    #pragma unroll
    for (int bb = 0; bb < NB; ++bb) {
        const int p = bb & 1;
        if (bb + 1 < NB) vload(bb + 1, p ^ 1);
        vstore(p);
        __syncthreads();

        #pragma unroll
        for (int s = 0; s < 2; ++s) {
            const int cb = bb * 64 + s * 8 + qd * 2;
            float2 p0 = *(const float2*)&kt[cb];
            float2 p1 = *(const float2*)&kt[cb + 16];
            float2 p2 = *(const float2*)&kt[cb + 32];
            float2 p3 = *(const float2*)&kt[cb + 48];
            float kj[8] = {p0.x, p1.x, p2.x, p3.x, p0.y, p1.y, p2.y, p3.y};

            union { short8 v; unsigned short u[8]; } A;
            #pragma unroll
            for (int j = 0; j < 8; ++j) {
                float ang = fn * kj[j];
                A.u[j] = f2bf(use_sin ? __sinf(ang) : __cosf(ang));
            }

            #pragma unroll
            for (int dt = 0; dt < 4; ++dt) {
                const int d = dt * 16 + fl;
                short8 B = *(const short8*)
                    &vtb[p][d * 64 + ((((s << 2) | qd) ^ (d & 7)) << 3)];
                acc[dt] = __builtin_amdgcn_mfma_f32_16x16x32_bf16(
                    A.v, B, acc[dt], 0, 0, 0);
            }
        }
    }

    float* Pb = P + ((size_t)chunk * 64 + bh) * (2 * NN * DD);
    #pragma unroll
    for (int dt = 0; dt < 4; ++dt)
        #pragma unroll
        for (int r = 0; r < 4; ++r)
            Pb[(w * 16 + qd * 4 + r) * DD + dt * 16 + fl] = acc[dt][r];
}

template <int NC>
__global__ __launch_bounds__(256) void k1_reduce(
    const float* __restrict__ P, float* __restrict__ CS)
{
    int gid = (blockIdx.x * 256 + threadIdx.x) * 4;
    float4 a = {0.f, 0.f, 0.f, 0.f};
    #pragma unroll
    for (int c = 0; c < NC; ++c) {
        float4 v = *(const float4*)&P[(size_t)c * (64 * 2 * NN * DD) + gid];
        a.x += v.x; a.y += v.y; a.z += v.z; a.w += v.w;
    }
    *(float4*)&CS[gid] = a;
}

__global__ __launch_bounds__(256) void k2_out(
    const float* __restrict__ query, const float* __restrict__ ramps,
    const float* __restrict__ iamps, const float* __restrict__ CS,
    float* __restrict__ out)
{
    const int bh = blockIdx.x >> 5;
    const int qc = blockIdx.x & 31;
    const int b = bh >> 4, h = bh & 15;
    const int qbase = qc * 128;
    const int tid = threadIdx.x;
    const int w = tid >> 6, l = tid & 63;

    __shared__ unsigned short cst[64 * 64];
    __shared__ float qv[128];

    {
        const float* CSb = CS + (size_t)bh * (2 * NN * DD);
        const int feat = tid >> 2, dbase = (tid & 3) * 16;
        const int fb = feat >> 3, f7 = feat & 7;
        #pragma unroll
        for (int i = 0; i < 4; ++i) {
            float4 v = *(const float4*)&CSb[feat * DD + dbase + i * 4];
            float vv[4] = {v.x, v.y, v.z, v.w};
            #pragma unroll
            for (int e = 0; e < 4; ++e) {
                int d = dbase + i * 4 + e;
                cst[d * 64 + ((fb ^ (d & 7)) << 3) + f7] = f2bf(vv[e]);
            }
        }
    }
    if (tid < 128)
        qv[tid] = query[(size_t)(b * SQ + qbase + tid) * HH + h];
    __syncthreads();

    const int fl = l & 15, qd = l >> 4;
    const int nb = qd * 8;
    float4 raA = *(const float4*)&ramps[h * NN + nb];
    float4 raB = *(const float4*)&ramps[h * NN + nb + 4];
    float4 iaA = *(const float4*)&iamps[h * NN + nb];
    float4 iaB = *(const float4*)&iamps[h * NN + nb + 4];
    float ra[8] = {raA.x, raA.y, raA.z, raA.w, raB.x, raB.y, raB.z, raB.w};
    float ia[8] = {iaA.x, iaA.y, iaA.z, iaA.w, iaB.x, iaB.y, iaB.z, iaB.w};

    union AB { short8 v; unsigned short u[8]; };
    AB A0[2], A1[2];
    #pragma unroll
    for (int hh = 0; hh < 2; ++hh) {
        const float qval = qv[hh * 64 + w * 16 + fl];
        #pragma unroll
        for (int j = 0; j < 8; ++j) {
            float s, c;
            __sincosf(freq_of(nb + j) * qval, &s, &c);
            A0[hh].u[j] = f2bf(ra[j] * c + ia[j] * s);
            A1[hh].u[j] = f2bf(ra[j] * s - ia[j] * c);
        }
    }

    floatx4 acc[2][4];
    #pragma unroll
    for (int hh = 0; hh < 2; ++hh)
        #pragma unroll
        for (int dt = 0; dt < 4; ++dt) acc[hh][dt] = (floatx4){0.f, 0.f, 0.f, 0.f};

    #pragma unroll
    for (int dt = 0; dt < 4; ++dt) {
        const int d = dt * 16 + fl;
        short8 B0 = *(const short8*)&cst[d * 64 + ((qd ^ (d & 7)) << 3)];
        short8 B1 = *(const short8*)&cst[d * 64 + (((4 + qd) ^ (d & 7)) << 3)];
        #pragma unroll
        for (int hh = 0; hh < 2; ++hh) {
            acc[hh][dt] = __builtin_amdgcn_mfma_f32_16x16x32_bf16(
                A0[hh].v, B0, acc[hh][dt], 0, 0, 0);
            acc[hh][dt] = __builtin_amdgcn_mfma_f32_16x16x32_bf16(
                A1[hh].v, B1, acc[hh][dt], 0, 0, 0);
        }
    }

    float* ob = out + ((size_t)(b * SQ + qbase) * HH + h) * DD;
    #pragma unroll
    for (int hh = 0; hh < 2; ++hh)
        #pragma unroll
        for (int dt = 0; dt < 4; ++dt)
            #pragma unroll
            for (int r = 0; r < 4; ++r) {
                int q = hh * 64 + w * 16 + qd * 4 + r;
                ob[(size_t)q * (HH * DD) + dt * 16 + fl] = acc[hh][dt][r];
            }
}

extern "C" void kernel_launch(void* const* d_in, const int* in_sizes, int n_in,
                              void* d_out, int out_size, void* d_ws, size_t ws_size,
                              hipStream_t stream) {
    const float* key_in = (const float*)d_in[0];
    const float* value  = (const float*)d_in[1];
    const float* query  = (const float*)d_in[2];
    const float* ramps  = (const float*)d_in[3];
    const float* iamps  = (const float*)d_in[4];
    float* out = (float*)d_out;

    const size_t CS_FLOATS  = 64 * 2 * NN * DD;            // 262144
    const size_t P16_FLOATS = (size_t)16 * CS_FLOATS;      // ~16.8 MB
    const size_t need16 = (P16_FLOATS + CS_FLOATS) * sizeof(float);

    float* P = (float*)d_ws;

    if (ws_size >= need16) {
        float* CSp = P + P16_FLOATS;
        void* args[] = {(void*)&key_in, (void*)&value, (void*)&query,
                        (void*)&ramps, (void*)&iamps,
                        (void*)&P, (void*)&CSp, (void*)&out};
        hipError_t e = hipLaunchCooperativeKernel(
            (const void*)fused, dim3(1024), dim3(256), args, 0, stream);
        if (e == hipSuccess) return;
        (void)hipGetLastError();           // clear, fall back to 3-kernel path

        hipLaunchKernelGGL((k1_partial<16>), dim3(64 * 16), dim3(256), 0, stream,
                           key_in, value, P);
        hipLaunchKernelGGL((k1_reduce<16>), dim3(CS_FLOATS / 1024), dim3(256), 0, stream,
                           P, CSp);
        hipLaunchKernelGGL(k2_out, dim3(64 * 32), dim3(256), 0, stream,
                           query, ramps, iamps, CSp, out);
    } else {
        float* CSp = P + (size_t)8 * CS_FLOATS;
        hipLaunchKernelGGL((k1_partial<8>), dim3(64 * 8), dim3(256), 0, stream,
                           key_in, value, P);
        hipLaunchKernelGGL((k1_reduce<8>), dim3(CS_FLOATS / 1024), dim3(256), 0, stream,
                           P, CSp);
        hipLaunchKernelGGL(k2_out, dim3(64 * 32), dim3(256), 0, stream,
                           query, ramps, iamps, CSp, out);
    }
}

// Round 5
// 134.594 us; speedup vs baseline: 2.6502x; 2.6502x over previous
//
#include <hip/hip_runtime.h>
#include <math.h>

// Problem constants (B, SK, SQ, H, D, N) = (4, 4096, 4096, 16, 64, 32)
#define SK 4096
#define SQ 4096
#define HH 16
#define DD 64
#define NN 32

typedef __attribute__((ext_vector_type(8))) short short8;   // 8 bf16 = 4 VGPRs
typedef __attribute__((ext_vector_type(4))) float floatx4;  // MFMA C/D
typedef __attribute__((ext_vector_type(4))) unsigned short us4;

// freqs[n] = (n / (N-1)) * N * pi
__device__ __forceinline__ float freq_of(int n) {
    return (float)n * (32.0f * (float)M_PI / 31.0f);
}

// fp32 -> bf16 (round to nearest even), as raw ushort
__device__ __forceinline__ unsigned short f2bf(float x) {
    unsigned u = __float_as_uint(x);
    u += 0x7FFFu + ((u >> 16) & 1u);
    return (unsigned short)(u >> 16);
}

// ---------------------------------------------------------------------------
// Kernel 1 (MFMA, verified round-1): partial C/S per (bh, chunk).
// feat 0-31 = cos_n, 32-63 = sin_n.  4 waves; wave w owns feats 16w..16w+15.
// V reg-staged (coalesced float4, double-buffered), converted to bf16 once,
// stored k'-contiguous + XOR-swizzled so B-frags are single ds_read_b128.
//   k' = (k&15)*4 + (k>>4);  A built from kt in the SAME permuted k-order
//   k(s,qd,j) = (j&3)*16 + 8s + 2qd + (j>>2)  so A/B agree per (qd, j).
// ---------------------------------------------------------------------------
template <int NC>
__global__ __launch_bounds__(256) void k1_partial(
    const float* __restrict__ key_in, const float* __restrict__ value,
    float* __restrict__ P)
{
    constexpr int KPC = SK / NC;
    constexpr int NB  = KPC / 64;          // 64-key tiles
    const int chunk = blockIdx.x & (NC - 1);
    const int bh    = blockIdx.x / NC;
    const int b = bh >> 4, h = bh & 15;
    const int tid = threadIdx.x;
    const int w = tid >> 6, l = tid & 63;

    __shared__ unsigned short vtb[2][64 * 64];  // 2 x 8 KB bf16 V, k'-major swizzled
    __shared__ float kt[KPC];                   // chunk keys

    const int k0 = chunk * KPC;
    const int g  = tid & 15;               // d quad (d = 4g..4g+3)
    const int kq = tid >> 4;               // 0..15 (k' block)

    #pragma unroll
    for (int i = 0; i < KPC / 256; ++i)
        kt[tid + i * 256] = key_in[(size_t)(b * SK + k0 + tid + i * 256) * HH + h];

    const int fl = l & 15;                 // feat_local (A) / d_local (B,D)
    const int qd = l >> 4;                 // quad
    const int feat = w * 16 + fl;
    const float fn = freq_of(feat & 31);
    const bool use_sin = (w >= 2);

    floatx4 acc[4];
    #pragma unroll
    for (int dt = 0; dt < 4; ++dt) acc[dt] = (floatx4){0.f, 0.f, 0.f, 0.f};

    union F4 { float4 v; float f[4]; };
    F4 L[2][4];

    auto vload = [&](int bb, int p) {      // 4 coalesced float4 per thread
        const int kb = k0 + bb * 64;
        #pragma unroll
        for (int jj = 0; jj < 4; ++jj)
            L[p][jj].v = *(const float4*)(value
                + (size_t)(b * SK + kb + jj * 16 + kq) * (HH * DD) + h * DD + g * 4);
    };
    auto vstore = [&](int p) {             // cvt + packed b64 writes (swizzled)
        #pragma unroll
        for (int e = 0; e < 4; ++e) {
            const int d = g * 4 + e;
            union { us4 v; unsigned short u[4]; } px;
            #pragma unroll
            for (int jj = 0; jj < 4; ++jj)
                px.u[jj] = f2bf(L[p][jj].f[e]);
            *(us4*)&vtb[p][d * 64 + ((((kq >> 1) ^ (d & 7)) << 3) | ((kq & 1) << 2))]
                = px.v;
        }
    };

    vload(0, 0);
    #pragma unroll
    for (int bb = 0; bb < NB; ++bb) {
        const int p = bb & 1;
        if (bb + 1 < NB) vload(bb + 1, p ^ 1);   // issue next tile early (T14)
        vstore(p);
        __syncthreads();                         // vtb[p] + kt ready

        #pragma unroll
        for (int s = 0; s < 2; ++s) {      // 2 K-steps of 32 keys (k'-order)
            const int cb = bb * 64 + s * 8 + qd * 2;
            float2 p0 = *(const float2*)&kt[cb];
            float2 p1 = *(const float2*)&kt[cb + 16];
            float2 p2 = *(const float2*)&kt[cb + 32];
            float2 p3 = *(const float2*)&kt[cb + 48];
            float kj[8] = {p0.x, p1.x, p2.x, p3.x, p0.y, p1.y, p2.y, p3.y};

            union { short8 v; unsigned short u[8]; } A;
            #pragma unroll
            for (int j = 0; j < 8; ++j) {
                float ang = fn * kj[j];
                A.u[j] = f2bf(use_sin ? __sinf(ang) : __cosf(ang));
            }

            #pragma unroll
            for (int dt = 0; dt < 4; ++dt) {
                const int d = dt * 16 + fl;
                short8 B = *(const short8*)
                    &vtb[p][d * 64 + ((((s << 2) | qd) ^ (d & 7)) << 3)];
                acc[dt] = __builtin_amdgcn_mfma_f32_16x16x32_bf16(
                    A.v, B, acc[dt], 0, 0, 0);
            }
        }
    }

    float* Pb = P + ((size_t)chunk * 64 + bh) * (2 * NN * DD);
    #pragma unroll
    for (int dt = 0; dt < 4; ++dt)
        #pragma unroll
        for (int r = 0; r < 4; ++r)
            Pb[(w * 16 + qd * 4 + r) * DD + dt * 16 + fl] = acc[dt][r];
}

// ---------------------------------------------------------------------------
// Kernel 1b: reduce chunk partials AND emit CS as bf16, pre-swizzled in the
// exact [d][feat] image k2 stages to LDS:  pos = d*64 + ((fb^(d&7))<<3) + f7.
// Thread: 4 consecutive d of one feat (float4 over chunks), 4 ushort stores.
// ---------------------------------------------------------------------------
template <int NC>
__global__ __launch_bounds__(256) void k1_reduce_bf16(
    const float* __restrict__ P, unsigned short* __restrict__ CSb)
{
    const int gid4 = (blockIdx.x * 256 + threadIdx.x) * 4;
    float4 a = {0.f, 0.f, 0.f, 0.f};
    #pragma unroll
    for (int c = 0; c < NC; ++c) {
        float4 v = *(const float4*)&P[(size_t)c * (64 * 2 * NN * DD) + gid4];
        a.x += v.x; a.y += v.y; a.z += v.z; a.w += v.w;
    }
    const int bh = gid4 >> 12;
    const int feat = (gid4 >> 6) & 63;
    const int d0 = gid4 & 63;
    const int fb = feat >> 3, f7 = feat & 7;
    unsigned short* o = CSb + (size_t)bh * (2 * NN * DD);
    float av[4] = {a.x, a.y, a.z, a.w};
    #pragma unroll
    for (int e = 0; e < 4; ++e) {
        const int d = d0 + e;
        o[d * 64 + ((fb ^ (d & 7)) << 3) + f7] = f2bf(av[e]);
    }
}

// ---------------------------------------------------------------------------
// Kernel 2 (MFMA): out[q][d] = sum_feat Aq[q][feat] * CS[feat][d], K = 64.
// 256 q per block: CS staged via a straight 8 KB copy (TWO uint4 per thread
// = 512 uint4 total covering the full 64x64 tile), B-frags loaded once into
// registers and reused 4x; A-frags rebuilt per 128-q half.
// ---------------------------------------------------------------------------
__global__ __launch_bounds__(256) void k2_out(
    const float* __restrict__ query, const float* __restrict__ ramps,
    const float* __restrict__ iamps, const unsigned short* __restrict__ CSb,
    float* __restrict__ out)
{
    const int bh = blockIdx.x >> 4;
    const int q0 = (blockIdx.x & 15) * 256;
    const int b = bh >> 4, h = bh & 15;
    const int tid = threadIdx.x;
    const int w = tid >> 6, l = tid & 63;
    const int fl = l & 15, qd = l >> 4;

    __shared__ unsigned short cst[64 * 64];   // 8 KB bf16 CS^T (swizzled image)
    __shared__ float qv[256];

    // stage: straight copy 8 KB = 512 uint4 (2 per thread) + q gather
    {
        const uint4* src = (const uint4*)(CSb + (size_t)bh * (2 * NN * DD));
        *(uint4*)&cst[tid * 8]        = src[tid];
        *(uint4*)&cst[2048 + tid * 8] = src[256 + tid];
    }
    qv[tid] = query[(size_t)(b * SQ + q0 + tid) * HH + h];
    __syncthreads();

    const int nb = qd * 8;
    float4 raA = *(const float4*)&ramps[h * NN + nb];
    float4 raB = *(const float4*)&ramps[h * NN + nb + 4];
    float4 iaA = *(const float4*)&iamps[h * NN + nb];
    float4 iaB = *(const float4*)&iamps[h * NN + nb + 4];
    float ra[8] = {raA.x, raA.y, raA.z, raA.w, raB.x, raB.y, raB.z, raB.w};
    float ia[8] = {iaA.x, iaA.y, iaA.z, iaA.w, iaB.x, iaB.y, iaB.z, iaB.w};

    short8 B0[4], B1[4];                   // held in regs, reused 4x
    #pragma unroll
    for (int dt = 0; dt < 4; ++dt) {
        const int d = dt * 16 + fl;
        B0[dt] = *(const short8*)&cst[d * 64 + ((qd ^ (d & 7)) << 3)];
        B1[dt] = *(const short8*)&cst[d * 64 + (((4 + qd) ^ (d & 7)) << 3)];
    }

    #pragma unroll
    for (int qq = 0; qq < 2; ++qq) {
        union AB { short8 v; unsigned short u[8]; };
        AB A0[2], A1[2];
        #pragma unroll
        for (int hh = 0; hh < 2; ++hh) {
            const float qval = qv[qq * 128 + hh * 64 + w * 16 + fl];
            #pragma unroll
            for (int j = 0; j < 8; ++j) {
                float s, c;
                __sincosf(freq_of(nb + j) * qval, &s, &c);
                A0[hh].u[j] = f2bf(ra[j] * c + ia[j] * s);   // vs C rows (feats 0-31)
                A1[hh].u[j] = f2bf(ra[j] * s - ia[j] * c);   // vs S rows (feats 32-63)
            }
        }

        floatx4 acc[2][4];
        #pragma unroll
        for (int hh = 0; hh < 2; ++hh)
            #pragma unroll
            for (int dt = 0; dt < 4; ++dt)
                acc[hh][dt] = (floatx4){0.f, 0.f, 0.f, 0.f};

        #pragma unroll
        for (int dt = 0; dt < 4; ++dt)
            #pragma unroll
            for (int hh = 0; hh < 2; ++hh) {
                acc[hh][dt] = __builtin_amdgcn_mfma_f32_16x16x32_bf16(
                    A0[hh].v, B0[dt], acc[hh][dt], 0, 0, 0);
                acc[hh][dt] = __builtin_amdgcn_mfma_f32_16x16x32_bf16(
                    A1[hh].v, B1[dt], acc[hh][dt], 0, 0, 0);
            }

        float* ob = out + ((size_t)(b * SQ + q0 + qq * 128) * HH + h) * DD;
        #pragma unroll
        for (int hh = 0; hh < 2; ++hh)
            #pragma unroll
            for (int dt = 0; dt < 4; ++dt)
                #pragma unroll
                for (int r = 0; r < 4; ++r) {
                    int q = hh * 64 + w * 16 + qd * 4 + r;   // D row = q
                    ob[(size_t)q * (HH * DD) + dt * 16 + fl] = acc[hh][dt][r];
                }
    }
}

extern "C" void kernel_launch(void* const* d_in, const int* in_sizes, int n_in,
                              void* d_out, int out_size, void* d_ws, size_t ws_size,
                              hipStream_t stream) {
    const float* key_in = (const float*)d_in[0];
    const float* value  = (const float*)d_in[1];
    const float* query  = (const float*)d_in[2];
    const float* ramps  = (const float*)d_in[3];
    const float* iamps  = (const float*)d_in[4];
    float* out = (float*)d_out;

    const size_t CS_FLOATS  = 64 * 2 * NN * DD;            // 262144
    const size_t P16_FLOATS = (size_t)16 * CS_FLOATS;      // ~16.8 MB
    const size_t need16 = P16_FLOATS * sizeof(float) + CS_FLOATS * sizeof(unsigned short);

    float* P = (float*)d_ws;

    if (ws_size >= need16) {
        unsigned short* CSb = (unsigned short*)(P + P16_FLOATS);
        hipLaunchKernelGGL((k1_partial<16>), dim3(64 * 16), dim3(256), 0, stream,
                           key_in, value, P);
        hipLaunchKernelGGL((k1_reduce_bf16<16>), dim3(CS_FLOATS / 1024), dim3(256), 0,
                           stream, P, CSb);
        hipLaunchKernelGGL(k2_out, dim3(64 * 16), dim3(256), 0, stream,
                           query, ramps, iamps, CSb, out);
    } else {
        unsigned short* CSb = (unsigned short*)(P + (size_t)8 * CS_FLOATS);
        hipLaunchKernelGGL((k1_partial<8>), dim3(64 * 8), dim3(256), 0, stream,
                           key_in, value, P);
        hipLaunchKernelGGL((k1_reduce_bf16<8>), dim3(CS_FLOATS / 1024), dim3(256), 0,
                           stream, P, CSb);
        hipLaunchKernelGGL(k2_out, dim3(64 * 16), dim3(256), 0, stream,
                           query, ramps, iamps, CSb, out);
    }
}

// Round 6
// 131.996 us; speedup vs baseline: 2.7024x; 1.0197x over previous
//
#include <hip/hip_runtime.h>
#include <math.h>

// Problem constants (B, SK, SQ, H, D, N) = (4, 4096, 4096, 16, 64, 32)
#define SK 4096
#define SQ 4096
#define HH 16
#define DD 64
#define NN 32

typedef __attribute__((ext_vector_type(8))) short short8;   // 8 bf16 = 4 VGPRs
typedef __attribute__((ext_vector_type(4))) float floatx4;  // MFMA C/D
typedef __attribute__((ext_vector_type(4))) unsigned short us4;

// freqs[n] = (n / (N-1)) * N * pi
__device__ __forceinline__ float freq_of(int n) {
    return (float)n * (32.0f * (float)M_PI / 31.0f);
}

// fp32 -> bf16 (round to nearest even), as raw ushort
__device__ __forceinline__ unsigned short f2bf(float x) {
    unsigned u = __float_as_uint(x);
    u += 0x7FFFu + ((u >> 16) & 1u);
    return (unsigned short)(u >> 16);
}

// ---------------------------------------------------------------------------
// Kernel 1 (MFMA, verified): partial C/S per (bh, chunk).
// feat 0-31 = cos_n, 32-63 = sin_n.  4 waves; wave w owns feats 16w..16w+15.
// V reg-staged (coalesced float4, double-buffered), converted to bf16 once,
// stored k'-contiguous + XOR-swizzled so B-frags are single ds_read_b128.
//   k' = (k&15)*4 + (k>>4);  A built from kt in the SAME permuted k-order
//   k(s,qd,j) = (j&3)*16 + 8s + 2qd + (j>>2)  so A/B agree per (qd, j).
// NC=8 this round: halves the P round-trip (the only discretionary HBM
// traffic); inner code is NC-independent.
// ---------------------------------------------------------------------------
template <int NC>
__global__ __launch_bounds__(256) void k1_partial(
    const float* __restrict__ key_in, const float* __restrict__ value,
    float* __restrict__ P)
{
    constexpr int KPC = SK / NC;
    constexpr int NB  = KPC / 64;          // 64-key tiles
    const int chunk = blockIdx.x & (NC - 1);
    const int bh    = blockIdx.x / NC;
    const int b = bh >> 4, h = bh & 15;
    const int tid = threadIdx.x;
    const int w = tid >> 6, l = tid & 63;

    __shared__ unsigned short vtb[2][64 * 64];  // 2 x 8 KB bf16 V, k'-major swizzled
    __shared__ float kt[KPC];                   // chunk keys

    const int k0 = chunk * KPC;
    const int g  = tid & 15;               // d quad (d = 4g..4g+3)
    const int kq = tid >> 4;               // 0..15 (k' block)

    #pragma unroll
    for (int i = 0; i < KPC / 256; ++i)
        kt[tid + i * 256] = key_in[(size_t)(b * SK + k0 + tid + i * 256) * HH + h];

    const int fl = l & 15;                 // feat_local (A) / d_local (B,D)
    const int qd = l >> 4;                 // quad
    const int feat = w * 16 + fl;
    const float fn = freq_of(feat & 31);
    const bool use_sin = (w >= 2);

    floatx4 acc[4];
    #pragma unroll
    for (int dt = 0; dt < 4; ++dt) acc[dt] = (floatx4){0.f, 0.f, 0.f, 0.f};

    union F4 { float4 v; float f[4]; };
    F4 L[2][4];

    auto vload = [&](int bb, int p) {      // 4 coalesced float4 per thread
        const int kb = k0 + bb * 64;
        #pragma unroll
        for (int jj = 0; jj < 4; ++jj)
            L[p][jj].v = *(const float4*)(value
                + (size_t)(b * SK + kb + jj * 16 + kq) * (HH * DD) + h * DD + g * 4);
    };
    auto vstore = [&](int p) {             // cvt + packed b64 writes (swizzled)
        #pragma unroll
        for (int e = 0; e < 4; ++e) {
            const int d = g * 4 + e;
            union { us4 v; unsigned short u[4]; } px;
            #pragma unroll
            for (int jj = 0; jj < 4; ++jj)
                px.u[jj] = f2bf(L[p][jj].f[e]);
            *(us4*)&vtb[p][d * 64 + ((((kq >> 1) ^ (d & 7)) << 3) | ((kq & 1) << 2))]
                = px.v;
        }
    };

    vload(0, 0);
    #pragma unroll
    for (int bb = 0; bb < NB; ++bb) {
        const int p = bb & 1;
        if (bb + 1 < NB) vload(bb + 1, p ^ 1);   // issue next tile early (T14)
        vstore(p);
        __syncthreads();                         // vtb[p] + kt ready

        #pragma unroll
        for (int s = 0; s < 2; ++s) {      // 2 K-steps of 32 keys (k'-order)
            const int cb = bb * 64 + s * 8 + qd * 2;
            float2 p0 = *(const float2*)&kt[cb];
            float2 p1 = *(const float2*)&kt[cb + 16];
            float2 p2 = *(const float2*)&kt[cb + 32];
            float2 p3 = *(const float2*)&kt[cb + 48];
            float kj[8] = {p0.x, p1.x, p2.x, p3.x, p0.y, p1.y, p2.y, p3.y};

            union { short8 v; unsigned short u[8]; } A;
            #pragma unroll
            for (int j = 0; j < 8; ++j) {
                float ang = fn * kj[j];
                A.u[j] = f2bf(use_sin ? __sinf(ang) : __cosf(ang));
            }

            #pragma unroll
            for (int dt = 0; dt < 4; ++dt) {
                const int d = dt * 16 + fl;
                short8 B = *(const short8*)
                    &vtb[p][d * 64 + ((((s << 2) | qd) ^ (d & 7)) << 3)];
                acc[dt] = __builtin_amdgcn_mfma_f32_16x16x32_bf16(
                    A.v, B, acc[dt], 0, 0, 0);
            }
        }
    }

    float* Pb = P + ((size_t)chunk * 64 + bh) * (2 * NN * DD);
    #pragma unroll
    for (int dt = 0; dt < 4; ++dt)
        #pragma unroll
        for (int r = 0; r < 4; ++r)
            Pb[(w * 16 + qd * 4 + r) * DD + dt * 16 + fl] = acc[dt][r];
}

// ---------------------------------------------------------------------------
// Kernel 1b: reduce chunk partials AND emit CS as bf16, pre-swizzled in the
// exact [d][feat] image k2 stages to LDS:  pos = d*64 + ((fb^(d&7))<<3) + f7.
// Thread: 4 consecutive d of one feat (float4 over chunks), 4 ushort stores.
// ---------------------------------------------------------------------------
template <int NC>
__global__ __launch_bounds__(256) void k1_reduce_bf16(
    const float* __restrict__ P, unsigned short* __restrict__ CSb)
{
    const int gid4 = (blockIdx.x * 256 + threadIdx.x) * 4;
    float4 a = {0.f, 0.f, 0.f, 0.f};
    #pragma unroll
    for (int c = 0; c < NC; ++c) {
        float4 v = *(const float4*)&P[(size_t)c * (64 * 2 * NN * DD) + gid4];
        a.x += v.x; a.y += v.y; a.z += v.z; a.w += v.w;
    }
    const int bh = gid4 >> 12;
    const int feat = (gid4 >> 6) & 63;
    const int d0 = gid4 & 63;
    const int fb = feat >> 3, f7 = feat & 7;
    unsigned short* o = CSb + (size_t)bh * (2 * NN * DD);
    float av[4] = {a.x, a.y, a.z, a.w};
    #pragma unroll
    for (int e = 0; e < 4; ++e) {
        const int d = d0 + e;
        o[d * 64 + ((fb ^ (d & 7)) << 3) + f7] = f2bf(av[e]);
    }
}

// ---------------------------------------------------------------------------
// Kernel 2 (MFMA, verified round-5): out[q][d] = sum_f Aq[q][f]*CS[f][d], K=64.
// 256 q per block: CS staged via straight 8 KB copy (2 uint4/thread = full
// 64x64 tile), B-frags loaded once into registers and reused 4x.
// ---------------------------------------------------------------------------
__global__ __launch_bounds__(256) void k2_out(
    const float* __restrict__ query, const float* __restrict__ ramps,
    const float* __restrict__ iamps, const unsigned short* __restrict__ CSb,
    float* __restrict__ out)
{
    const int bh = blockIdx.x >> 4;
    const int q0 = (blockIdx.x & 15) * 256;
    const int b = bh >> 4, h = bh & 15;
    const int tid = threadIdx.x;
    const int w = tid >> 6, l = tid & 63;
    const int fl = l & 15, qd = l >> 4;

    __shared__ unsigned short cst[64 * 64];   // 8 KB bf16 CS^T (swizzled image)
    __shared__ float qv[256];

    // stage: straight copy 8 KB = 512 uint4 (2 per thread) + q gather
    {
        const uint4* src = (const uint4*)(CSb + (size_t)bh * (2 * NN * DD));
        *(uint4*)&cst[tid * 8]        = src[tid];
        *(uint4*)&cst[2048 + tid * 8] = src[256 + tid];
    }
    qv[tid] = query[(size_t)(b * SQ + q0 + tid) * HH + h];
    __syncthreads();

    const int nb = qd * 8;
    float4 raA = *(const float4*)&ramps[h * NN + nb];
    float4 raB = *(const float4*)&ramps[h * NN + nb + 4];
    float4 iaA = *(const float4*)&iamps[h * NN + nb];
    float4 iaB = *(const float4*)&iamps[h * NN + nb + 4];
    float ra[8] = {raA.x, raA.y, raA.z, raA.w, raB.x, raB.y, raB.z, raB.w};
    float ia[8] = {iaA.x, iaA.y, iaA.z, iaA.w, iaB.x, iaB.y, iaB.z, iaB.w};

    short8 B0[4], B1[4];                   // held in regs, reused 4x
    #pragma unroll
    for (int dt = 0; dt < 4; ++dt) {
        const int d = dt * 16 + fl;
        B0[dt] = *(const short8*)&cst[d * 64 + ((qd ^ (d & 7)) << 3)];
        B1[dt] = *(const short8*)&cst[d * 64 + (((4 + qd) ^ (d & 7)) << 3)];
    }

    #pragma unroll
    for (int qq = 0; qq < 2; ++qq) {
        union AB { short8 v; unsigned short u[8]; };
        AB A0[2], A1[2];
        #pragma unroll
        for (int hh = 0; hh < 2; ++hh) {
            const float qval = qv[qq * 128 + hh * 64 + w * 16 + fl];
            #pragma unroll
            for (int j = 0; j < 8; ++j) {
                float s, c;
                __sincosf(freq_of(nb + j) * qval, &s, &c);
                A0[hh].u[j] = f2bf(ra[j] * c + ia[j] * s);   // vs C rows (feats 0-31)
                A1[hh].u[j] = f2bf(ra[j] * s - ia[j] * c);   // vs S rows (feats 32-63)
            }
        }

        floatx4 acc[2][4];
        #pragma unroll
        for (int hh = 0; hh < 2; ++hh)
            #pragma unroll
            for (int dt = 0; dt < 4; ++dt)
                acc[hh][dt] = (floatx4){0.f, 0.f, 0.f, 0.f};

        #pragma unroll
        for (int dt = 0; dt < 4; ++dt)
            #pragma unroll
            for (int hh = 0; hh < 2; ++hh) {
                acc[hh][dt] = __builtin_amdgcn_mfma_f32_16x16x32_bf16(
                    A0[hh].v, B0[dt], acc[hh][dt], 0, 0, 0);
                acc[hh][dt] = __builtin_amdgcn_mfma_f32_16x16x32_bf16(
                    A1[hh].v, B1[dt], acc[hh][dt], 0, 0, 0);
            }

        float* ob = out + ((size_t)(b * SQ + q0 + qq * 128) * HH + h) * DD;
        #pragma unroll
        for (int hh = 0; hh < 2; ++hh)
            #pragma unroll
            for (int dt = 0; dt < 4; ++dt)
                #pragma unroll
                for (int r = 0; r < 4; ++r) {
                    int q = hh * 64 + w * 16 + qd * 4 + r;   // D row = q
                    ob[(size_t)q * (HH * DD) + dt * 16 + fl] = acc[hh][dt][r];
                }
    }
}

extern "C" void kernel_launch(void* const* d_in, const int* in_sizes, int n_in,
                              void* d_out, int out_size, void* d_ws, size_t ws_size,
                              hipStream_t stream) {
    const float* key_in = (const float*)d_in[0];
    const float* value  = (const float*)d_in[1];
    const float* query  = (const float*)d_in[2];
    const float* ramps  = (const float*)d_in[3];
    const float* iamps  = (const float*)d_in[4];
    float* out = (float*)d_out;

    const size_t CS_FLOATS = 64 * 2 * NN * DD;             // 262144
    const size_t P8_FLOATS = (size_t)8 * CS_FLOATS;        // ~8.4 MB
    const size_t need8 = P8_FLOATS * sizeof(float) + CS_FLOATS * sizeof(unsigned short);

    float* P = (float*)d_ws;
    unsigned short* CSb = (unsigned short*)(P + P8_FLOATS);
    (void)need8; (void)ws_size;            // ws is ~268 MB >> need8 (~9 MB)

    hipLaunchKernelGGL((k1_partial<8>), dim3(64 * 8), dim3(256), 0, stream,
                       key_in, value, P);
    hipLaunchKernelGGL((k1_reduce_bf16<8>), dim3(CS_FLOATS / 1024), dim3(256), 0,
                       stream, P, CSb);
    hipLaunchKernelGGL(k2_out, dim3(64 * 16), dim3(256), 0, stream,
                       query, ramps, iamps, CSb, out);
}